// Round 9
// baseline (316.751 us; speedup 1.0000x reference)
//
#include <hip/hip_runtime.h>
#include <cstdint>

#define B_ 2
#define E_ 16
#define H_ 160
#define W_ 288
#define N_ 12
#define T_ 2
#define HW_ (H_*W_)        // 46080
#define P_ (T_*HW_)        // 92160
#define NINST (B_*N_)      // 24
#define NBINS 1024         // err in [0,2] -> bin = min(1023, err*512)
#define BINSCALE 512.0f
#define CHUNK 1536         // px per block; 30 chunks/frame, 60/instance
#define NCHUNK 60
#define NGROUPS 120        // (b,chunk) groups: 2 * 60
#define GRID_SWZ 1440      // 8 xcd * 15 gslots * 12 instances (bijective, no padding)
#define ASTRIDE 36         // instAcc slot stride (33 floats used)

typedef unsigned long long u64;
typedef unsigned int u32;

__device__ inline float waveReduceSum(float v){
  #pragma unroll
  for(int o=32;o>0;o>>=1) v += __shfl_down(v, o, 64);
  return v;
}

// Fold-reduction: sum v[0..15] across 64 lanes in 15+2 shuffles.
// Result: every lane holds the 64-lane sum of e = bitrev4(lane&15).
#define FOLD_STEP(m, half) \
  { bool hi = (lane & (m)) != 0; \
    _Pragma("unroll") \
    for(int i=0;i<(half);i++){ \
      float send = hi ? v[i] : v[i+(half)]; \
      float recv = __shfl_xor(send, (m), 64); \
      v[i] = (hi ? v[i+(half)] : v[i]) + recv; } }

__device__ inline float fold16sum(float* v, int lane){
  FOLD_STEP(1,8) FOLD_STEP(2,4) FOLD_STEP(4,2) FOLD_STEP(8,1)
  float r = v[0];
  r += __shfl_xor(r, 16, 64);
  r += __shfl_xor(r, 32, 64);
  return r;
}

// XCD swizzle: the 12 instance-blocks sharing one (b,chunk) emb tile are
// congruent mod 8 -> same XCD L2. 120 groups / 8 = 15 gslots, bijective.
__device__ inline void decode_blk(int lid, int& bn, int& t, int& rbase){
  int xcd = lid & 7, k = lid >> 3;
  int j = k % 12, gslot = k / 12;       // gslot 0..14
  int g = xcd + 8*gslot;                // 0..119
  int b = g & 1, y = g >> 1;            // y = chunk 0..59
  bn = b*N_ + j;
  t = y / 30;
  rbase = (y - t*30) * CHUNK;
}

// ---- Fused stats+err kernel. All 1440 blocks are co-resident by
// construction (1536 thr/CU <= 2048; 6 x 8.2KB LDS <= 160KB; VGPR <= 341 via
// launch_bounds(256,6)) -> per-instance spin-wait is scheduling-safe.
// Phase 1: chunk -> registers, masked sum/sumsq/count -> device-scope
//   atomicAdd into instAcc[bn] (performed at coherent point), then
//   vmcnt(0) + relaxed agent increment of done[bn]  (release, no wbl2).
// Phase 2: spin until done[bn]==60, read final sums (agent atomic loads,
//   same value for all blocks), mean/var, then d from REGISTERS (no global
//   re-read), LDS histogram, merge.
__global__ __launch_bounds__(256, 6) void k_fused(
    const float* __restrict__ mf1, const float* __restrict__ mf2,
    const int* __restrict__ gt,
    float* __restrict__ instAcc, u32* __restrict__ done,
    u64* __restrict__ hist, float* __restrict__ esum,
    float* __restrict__ out)
{
  __shared__ u32   hcl[NBINS];   // count<<16 | labelsum (block-local, fits 16b)
  __shared__ float hes[NBINS];
  __shared__ float red[2*E_+1];
  int lid = blockIdx.x, tid = threadIdx.x;
  if(lid == 0 && tid == 0) *out = 0.f;

  int bn, t, rbase;
  decode_blk(lid, bn, t, rbase);
  int b = bn / N_;
  int lane = tid & 63;

  const float* ep = (t ? mf2 : mf1) + (size_t)b*(E_*HW_);
  const int*   gp = gt + ((size_t)bn*T_ + t)*HW_ + rbase;

  // ---- load this block's 1536-px chunk into registers (static indexing)
  int4 m4 = *(const int4*)(gp + tid*4);
  int2 mm = *(const int2*)(gp + 1024 + tid*2);
  float4 xa[E_]; float2 xb[E_];
  #pragma unroll
  for(int e=0;e<E_;e++) xa[e] = *(const float4*)(ep + (size_t)e*HW_ + rbase + tid*4);
  #pragma unroll
  for(int e=0;e<E_;e++) xb[e] = *(const float2*)(ep + (size_t)e*HW_ + rbase + 1024 + tid*2);

  float ma0=(float)m4.x, ma1=(float)m4.y, ma2=(float)m4.z, ma3=(float)m4.w;
  float mb0=(float)mm.x, mb1=(float)mm.y;
  float c = ma0+ma1+ma2+ma3+mb0+mb1;

  // ---- phase 1: masked sum + sumsq
  float s[E_], q[E_];
  #pragma unroll
  for(int e=0;e<E_;e++){
    float4 x = xa[e]; float2 z = xb[e];
    float mx0=ma0*x.x; float se=mx0;      float qe=mx0*x.x;
    float mx1=ma1*x.y; se+=mx1; qe=fmaf(mx1,x.y,qe);
    float mx2=ma2*x.z; se+=mx2; qe=fmaf(mx2,x.z,qe);
    float mx3=ma3*x.w; se+=mx3; qe=fmaf(mx3,x.w,qe);
    float mz0=mb0*z.x; se+=mz0; qe=fmaf(mz0,z.x,qe);
    float mz1=mb1*z.y; se+=mz1; qe=fmaf(mz1,z.y,qe);
    s[e]=se; q[e]=qe;
  }

  if(tid < 2*E_+1) red[tid] = 0.f;
  __syncthreads();
  {
    float sf = fold16sum(s, lane);
    float qf = fold16sum(q, lane);
    float cf = waveReduceSum(c);
    int ee = ((lane&1)<<3)|((lane&2)<<1)|((lane&4)>>1)|((lane&8)>>3);  // bitrev4
    if(lane < 16){
      atomicAdd(&red[ee],    sf);
      atomicAdd(&red[E_+ee], qf);
    }
    if(lane == 0) atomicAdd(&red[2*E_], cf);
  }
  __syncthreads();
  // device-scope atomics -> coherent point; all issued by wave 0
  if(tid < 2*E_+1) atomicAdd(&instAcc[bn*ASTRIDE + tid], red[tid]);
  asm volatile("s_waitcnt vmcnt(0)" ::: "memory");   // order adds before release
  if(tid == 0)
    __hip_atomic_fetch_add(&done[bn], 1u, __ATOMIC_RELAXED, __HIP_MEMORY_SCOPE_AGENT);

  // zero LDS histogram while waiting
  for(int i=tid; i<NBINS; i+=256){ hcl[i]=0u; hes[i]=0.f; }

  // ---- per-instance spin (co-residency guaranteed; bailout-bounded)
  if(tid == 0){
    int guard = 0;
    while(__hip_atomic_load(&done[bn], __ATOMIC_RELAXED, __HIP_MEMORY_SCOPE_AGENT)
          < (u32)NCHUNK){
      if(++guard > (1<<24)) break;
      __builtin_amdgcn_s_sleep(2);
    }
  }
  __syncthreads();

  // ---- final sums (same value for every block of bn), mean/var
  if(tid < 2*E_+1)
    red[tid] = __hip_atomic_load(&instAcc[bn*ASTRIDE + tid],
                                 __ATOMIC_RELAXED, __HIP_MEMORY_SCOPE_AGENT);
  __syncthreads();
  if(tid < E_){
    float cc = red[2*E_];
    float mu = red[tid] / cc;
    float vv = (red[E_+tid] - cc*mu*mu) / (cc - 1.0f);
    red[tid] = mu; red[E_+tid] = vv;   // thread e only touches e, 16+e
  }
  __syncthreads();
  float mn[E_], sv[E_];
  #pragma unroll
  for(int e=0;e<E_;e++){ mn[e]=red[e]; sv[e]=red[E_+e]; }

  // ---- phase 2: err + histogram, entirely from registers
  float h0c=0.f,h0l=0.f,h0e=0.f, h1c=0.f,h1l=0.f,h1e=0.f;
  auto proc = [&](float d, int mi){
    float logits = 2.f*__expf(-0.5f*d) - 1.f;
    float ev = fmaxf(1.f - logits*(2.f*(float)mi - 1.f), 0.f);   // in [0,2]
    int bin = min(NBINS-1, (int)(ev * BINSCALE));
    if(bin == 0)            { h0c+=1.f; h0l+=(float)mi; h0e+=ev; }
    else if(bin == NBINS-1) { h1c+=1.f; h1l+=(float)mi; h1e+=ev; }
    else {
      atomicAdd(&hcl[bin], 0x10000u | (u32)mi);
      atomicAdd(&hes[bin], ev);
    }
  };

  {
    float d0=0.f,d1=0.f,d2=0.f,d3=0.f,d4=0.f,d5=0.f;
    #pragma unroll
    for(int e=0;e<E_;e++){
      float4 x = xa[e]; float2 z = xb[e];
      float mne=mn[e], sve=sv[e];
      float f0=x.x-mne; d0=fmaf(f0*f0, sve, d0);
      float f1=x.y-mne; d1=fmaf(f1*f1, sve, d1);
      float f2=x.z-mne; d2=fmaf(f2*f2, sve, d2);
      float f3=x.w-mne; d3=fmaf(f3*f3, sve, d3);
      float g0=z.x-mne; d4=fmaf(g0*g0, sve, d4);
      float g1=z.y-mne; d5=fmaf(g1*g1, sve, d5);
    }
    proc(d0,m4.x); proc(d1,m4.y); proc(d2,m4.z); proc(d3,m4.w);
    proc(d4,mm.x); proc(d5,mm.y);
  }

  // flush hot-bin registers (one wave-reduce, 4 LDS atomics per wave)
  h0c = waveReduceSum(h0c); h0l = waveReduceSum(h0l); h0e = waveReduceSum(h0e);
  h1c = waveReduceSum(h1c); h1l = waveReduceSum(h1l); h1e = waveReduceSum(h1e);
  if(lane == 0){
    if(h0c > 0.f){ atomicAdd(&hcl[0],       (((u32)h0c)<<16) | (u32)h0l); atomicAdd(&hes[0],       h0e); }
    if(h1c > 0.f){ atomicAdd(&hcl[NBINS-1], (((u32)h1c)<<16) | (u32)h1l); atomicAdd(&hes[NBINS-1], h1e); }
  }
  __syncthreads();

  // merge block-local histogram to global (pre-zeroed by memset; skip-empty)
  u64*   hp = hist + (size_t)bn*NBINS;
  float* sp = esum + (size_t)bn*NBINS;
  for(int i=tid; i<NBINS; i+=256){
    u32 v = hcl[i];
    if(v){
      atomicAdd(&hp[i], ((u64)(v>>16)<<32) | (u64)(v & 0xffffu));
      atomicAdd(&sp[i], hes[i]);
    }
  }
}

// ---- Pass C: per-instance descending bin scan + closed-form lovasz dot.
__global__ __launch_bounds__(256) void k_bins(const u64* __restrict__ hist,
                                              const float* __restrict__ esum,
                                              const float* __restrict__ instAcc,
                                              float* __restrict__ out){
  const int PT = NBINS/256;   // 4 bins per thread (reversed order)
  int bn = blockIdx.x;
  const u64*   h  = hist + (size_t)bn*NBINS;
  const float* es = esum + (size_t)bn*NBINS;
  int tid = threadIdx.x, lane = tid & 63, wave = tid >> 6;

  __shared__ float Gs;
  if(tid == 0) Gs = instAcc[bn*ASTRIDE + 2*E_];   // exact integer count

  u64 loc[PT]; u64 s = 0;
  #pragma unroll
  for(int k=0;k<PT;k++){
    loc[k] = h[NBINS-1 - (tid*PT + k)];
    s += loc[k];
  }
  u64 sc = s;
  #pragma unroll
  for(int off=1;off<64;off<<=1){ u64 v = __shfl_up(sc, off, 64); if(lane>=off) sc += v; }
  __shared__ u64 wsum[4], wbase[4];
  if(lane==63) wsum[wave] = sc;
  __syncthreads();
  if(tid==0){
    u64 run = 0;
    #pragma unroll
    for(int w=0;w<4;w++){ wbase[w] = run; run += wsum[w]; }
  }
  __syncthreads();
  u64 excl = wbase[wave] + (sc - s);

  float G = Gs;
  float lsum = 0.f;
  #pragma unroll
  for(int k=0;k<PT;k++){
    u64 lv = loc[k];
    u32 cb = (u32)(lv>>32), lb = (u32)(lv & 0xffffffffu);
    if(cb){
      float i0 = (float)(u32)(excl>>32);
      float c0 = (float)(u32)(excl & 0xffffffffu);
      float c1 = c0 + (float)lb;
      float jend   = 1.f - (G - c1)/(G + i0 + (float)cb - c1);
      float jstart = 1.f - (G - c0)/(G + i0 - c0);   // i0=0,c0=0 -> 0
      lsum += (es[NBINS-1 - (tid*PT + k)] / (float)cb) * (jend - jstart);
    }
    excl += lv;
  }

  __shared__ float rs[4];
  float tot = waveReduceSum(lsum);
  if(lane==0) rs[wave] = tot;
  __syncthreads();
  if(tid==0) atomicAdd(out, (rs[0]+rs[1]+rs[2]+rs[3]) * (1.0f/(float)NINST));
}

extern "C" void kernel_launch(void* const* d_in, const int* in_sizes, int n_in,
                              void* d_out, int out_size, void* d_ws, size_t ws_size,
                              hipStream_t stream){
  const float* mf1 = (const float*)d_in[0];
  const float* mf2 = (const float*)d_in[1];
  const int*   gt  = (const int*)d_in[2];
  float* out = (float*)d_out;

  // ws layout (one contiguous zeroed region)
  u64*   hist    = (u64*)d_ws;                          // 196608 B
  float* esum    = (float*)((char*)d_ws + 196608);      //  98304 B
  float* instAcc = (float*)((char*)d_ws + 294912);      //   3456 B (24*36*4)
  u32*   done    = (u32*)((char*)d_ws + 298368);        //     96 B
  size_t zbytes  = 298464;

  hipMemsetAsync(d_ws, 0, zbytes, stream);
  k_fused<<<GRID_SWZ, 256, 0, stream>>>(mf1, mf2, gt, instAcc, done, hist, esum, out);
  k_bins <<<NINST,   256, 0, stream>>>(hist, esum, instAcc, out);
}

// Round 10
// 209.860 us; speedup vs baseline: 1.5093x; 1.5093x over previous
//
#include <hip/hip_runtime.h>
#include <cstdint>

#define B_ 2
#define E_ 16
#define H_ 160
#define W_ 288
#define N_ 12
#define T_ 2
#define HW_ (H_*W_)        // 46080
#define P_ (T_*HW_)        // 92160
#define NINST (B_*N_)      // 24
#define NBINS 1024         // err in [0,2] -> bin = min(1023, err*512)
#define BINSCALE 512.0f
#define CHUNK 2304         // px per block; 20 chunks/frame, 40/instance
#define NCHUNK 40
#define GRID_SWZ 960       // 8 xcd * 10 gslots * 12 instances (bijective)
#define ASTRIDE 36         // instAcc slot stride (33 floats used)
#define HZ 26              // hist bins zeroed per block (40*26 >= 1024)

typedef unsigned long long u64;
typedef unsigned int u32;

__device__ inline float waveReduceSum(float v){
  #pragma unroll
  for(int o=32;o>0;o>>=1) v += __shfl_down(v, o, 64);
  return v;
}

// Fold-reduction: sum v[0..15] across 64 lanes in 15+2 shuffles.
// Result: every lane holds the 64-lane sum of e = bitrev4(lane&15).
#define FOLD_STEP(m, half) \
  { bool hi = (lane & (m)) != 0; \
    _Pragma("unroll") \
    for(int i=0;i<(half);i++){ \
      float send = hi ? v[i] : v[i+(half)]; \
      float recv = __shfl_xor(send, (m), 64); \
      v[i] = (hi ? v[i+(half)] : v[i]) + recv; } }

__device__ inline float fold16sum(float* v, int lane){
  FOLD_STEP(1,8) FOLD_STEP(2,4) FOLD_STEP(4,2) FOLD_STEP(8,1)
  float r = v[0];
  r += __shfl_xor(r, 16, 64);
  r += __shfl_xor(r, 32, 64);
  return r;
}

// XCD swizzle: the 12 instance-blocks sharing one (b,chunk) emb tile are
// congruent mod 8 -> same XCD L2. 80 groups / 8 = 10 gslots, bijective.
__device__ inline void decode_blk(int lid, int& bn, int& t, int& rbase, int& y_out){
  int xcd = lid & 7, k = lid >> 3;
  int j = k % 12, gslot = k / 12;       // gslot 0..9
  int g = xcd + 8*gslot;                // 0..79
  int b = g & 1, y = g >> 1;            // y = chunk 0..39
  bn = b*N_ + j;
  t = y / 20;
  rbase = (y - t*20) * CHUNK;
  y_out = y;
}

// ---- Fused kernel. Co-residency by construction: 960 blocks, <=4/CU;
// launch_bounds(256,4) -> 16 waves/CU -> VGPR cap 128 (kernel needs ~65,
// NO spill -- round 9's 458MB scratch disaster was the 24-wave/85-VGPR cap).
// Phase 1: chunk stats -> device atomicAdd instAcc[bn]; zero own hist slice;
//          vmcnt(0); done[bn]++ (release, no wbl2).
// Spin:    tid0 polls done[bn]==40 (agent-relaxed, s_sleep, guarded).
// Phase 2: mean/var from final instAcc (same value in all blocks); d from
//          L2-hot emb re-read (masks kept in regs); LDS histogram; merge.
// Tail:    last merging block per instance (merge_done counter) runs the
//          descending bin scan + lovasz dot inline. NO __threadfence.
__global__ __launch_bounds__(256, 4) void k_fused(
    const float* __restrict__ mf1, const float* __restrict__ mf2,
    const int* __restrict__ gt,
    float* __restrict__ instAcc, u32* __restrict__ done, u32* __restrict__ mdone,
    u64* __restrict__ hist, float* __restrict__ esum,
    float* __restrict__ out)
{
  __shared__ u32   hcl[NBINS];   // count<<16 | labelsum (block-local, fits 16b)
  __shared__ float hes[NBINS];
  __shared__ float red[2*E_+1];
  __shared__ u64 wsum[4], wbase[4];
  __shared__ float rs[4];
  __shared__ int lastFlag;
  int lid = blockIdx.x, tid = threadIdx.x;
  if(lid == 0 && tid == 0) *out = 0.f;

  int bn, t, rbase, y;
  decode_blk(lid, bn, t, rbase, y);
  int b = bn / N_;
  int lane = tid & 63, wave = tid >> 6;

  const float* ep = (t ? mf2 : mf1) + (size_t)b*(E_*HW_);
  const int*   gp = gt + ((size_t)bn*T_ + t)*HW_ + rbase;

  // masks for this thread's 9 px (kept in regs for phase 2)
  int4 mA = *(const int4*)(gp + tid*4);
  int4 mB = *(const int4*)(gp + 1024 + tid*4);
  int  mC = gp[2048 + tid];
  float a0=(float)mA.x, a1=(float)mA.y, a2=(float)mA.z, a3=(float)mA.w;
  float b0=(float)mB.x, b1=(float)mB.y, b2=(float)mB.z, b3=(float)mB.w;
  float c0=(float)mC;
  float c = a0+a1+a2+a3+b0+b1+b2+b3+c0;

  // ---- phase 1: masked sum + sumsq over 9 px/thread
  float s[E_], q[E_];
  #pragma unroll
  for(int e=0;e<E_;e++){
    const float* row = ep + (size_t)e*HW_ + rbase;
    float4 x = *(const float4*)(row + tid*4);
    float4 yv= *(const float4*)(row + 1024 + tid*4);
    float  z = row[2048 + tid];
    float m0=a0*x.x;  float se=m0;        float qe=m0*x.x;
    float m1=a1*x.y;  se+=m1; qe=fmaf(m1,x.y,qe);
    float m2=a2*x.z;  se+=m2; qe=fmaf(m2,x.z,qe);
    float m3=a3*x.w;  se+=m3; qe=fmaf(m3,x.w,qe);
    float n0=b0*yv.x; se+=n0; qe=fmaf(n0,yv.x,qe);
    float n1=b1*yv.y; se+=n1; qe=fmaf(n1,yv.y,qe);
    float n2=b2*yv.z; se+=n2; qe=fmaf(n2,yv.z,qe);
    float n3=b3*yv.w; se+=n3; qe=fmaf(n3,yv.w,qe);
    float p0=c0*z;    se+=p0; qe=fmaf(p0,z,qe);
    s[e]=se; q[e]=qe;
  }

  if(tid < 2*E_+1) red[tid] = 0.f;
  __syncthreads();
  {
    float sf = fold16sum(s, lane);
    float qf = fold16sum(q, lane);
    float cf = waveReduceSum(c);
    int ee = ((lane&1)<<3)|((lane&2)<<1)|((lane&4)>>1)|((lane&8)>>3);  // bitrev4
    if(lane < 16){
      atomicAdd(&red[ee],    sf);
      atomicAdd(&red[E_+ee], qf);
    }
    if(lane == 0) atomicAdd(&red[2*E_], cf);
  }
  __syncthreads();
  // device-scope accumulate (coherent point) + zero own hist slice
  if(tid < 2*E_+1) atomicAdd(&instAcc[bn*ASTRIDE + tid], red[tid]);
  if(tid < HZ){
    int idx = y*HZ + tid;
    if(idx < NBINS){
      hist[(size_t)bn*NBINS + idx] = 0ull;
      esum[(size_t)bn*NBINS + idx] = 0.f;
    }
  }
  asm volatile("s_waitcnt vmcnt(0)" ::: "memory");   // order adds+zeros before release
  if(tid == 0)
    __hip_atomic_fetch_add(&done[bn], 1u, __ATOMIC_RELAXED, __HIP_MEMORY_SCOPE_AGENT);

  // zero LDS histogram while waiting
  for(int i=tid; i<NBINS; i+=256){ hcl[i]=0u; hes[i]=0.f; }

  // ---- per-instance spin (all 960 blocks co-resident; bailout-bounded)
  if(tid == 0){
    int guard = 0;
    while(__hip_atomic_load(&done[bn], __ATOMIC_RELAXED, __HIP_MEMORY_SCOPE_AGENT)
          < (u32)NCHUNK){
      if(++guard > (1<<24)) break;
      __builtin_amdgcn_s_sleep(2);
    }
  }
  __syncthreads();

  // ---- final sums (identical value for every block of bn), mean/var
  if(tid < 2*E_+1)
    red[tid] = __hip_atomic_load(&instAcc[bn*ASTRIDE + tid],
                                 __ATOMIC_RELAXED, __HIP_MEMORY_SCOPE_AGENT);
  __syncthreads();
  if(tid < E_){
    float cc = red[2*E_];
    float mu = red[tid] / cc;
    float vv = (red[E_+tid] - cc*mu*mu) / (cc - 1.0f);
    red[tid] = mu; red[E_+tid] = vv;   // thread e only touches e, 16+e; red[32] kept
  }
  __syncthreads();
  float mn[E_], sv[E_];
  #pragma unroll
  for(int e=0;e<E_;e++){ mn[e]=red[e]; sv[e]=red[E_+e]; }

  // ---- phase 2: err + histogram; emb re-read is L2-hot (XCD swizzle)
  float h0c=0.f,h0l=0.f,h0e=0.f, h1c=0.f,h1l=0.f,h1e=0.f;
  auto proc = [&](float d, int mi){
    float logits = 2.f*__expf(-0.5f*d) - 1.f;
    float ev = fmaxf(1.f - logits*(2.f*(float)mi - 1.f), 0.f);   // in [0,2]
    int bin = min(NBINS-1, (int)(ev * BINSCALE));
    if(bin == 0)            { h0c+=1.f; h0l+=(float)mi; h0e+=ev; }
    else if(bin == NBINS-1) { h1c+=1.f; h1l+=(float)mi; h1e+=ev; }
    else {
      atomicAdd(&hcl[bin], 0x10000u | (u32)mi);
      atomicAdd(&hes[bin], ev);
    }
  };
  {
    float d0=0.f,d1=0.f,d2=0.f,d3=0.f,d4=0.f,d5=0.f,d6=0.f,d7=0.f,d8=0.f;
    #pragma unroll
    for(int e=0;e<E_;e++){
      const float* row = ep + (size_t)e*HW_ + rbase;
      float4 x = *(const float4*)(row + tid*4);
      float4 yv= *(const float4*)(row + 1024 + tid*4);
      float  z = row[2048 + tid];
      float mne=mn[e], sve=sv[e];
      float f0=x.x-mne;  d0=fmaf(f0*f0, sve, d0);
      float f1=x.y-mne;  d1=fmaf(f1*f1, sve, d1);
      float f2=x.z-mne;  d2=fmaf(f2*f2, sve, d2);
      float f3=x.w-mne;  d3=fmaf(f3*f3, sve, d3);
      float g0=yv.x-mne; d4=fmaf(g0*g0, sve, d4);
      float g1=yv.y-mne; d5=fmaf(g1*g1, sve, d5);
      float g2=yv.z-mne; d6=fmaf(g2*g2, sve, d6);
      float g3=yv.w-mne; d7=fmaf(g3*g3, sve, d7);
      float h0=z-mne;    d8=fmaf(h0*h0, sve, d8);
    }
    proc(d0,mA.x); proc(d1,mA.y); proc(d2,mA.z); proc(d3,mA.w);
    proc(d4,mB.x); proc(d5,mB.y); proc(d6,mB.z); proc(d7,mB.w);
    proc(d8,mC);
  }

  // flush hot-bin registers (one wave-reduce, 4 LDS atomics per wave)
  h0c = waveReduceSum(h0c); h0l = waveReduceSum(h0l); h0e = waveReduceSum(h0e);
  h1c = waveReduceSum(h1c); h1l = waveReduceSum(h1l); h1e = waveReduceSum(h1e);
  if(lane == 0){
    if(h0c > 0.f){ atomicAdd(&hcl[0],       (((u32)h0c)<<16) | (u32)h0l); atomicAdd(&hes[0],       h0e); }
    if(h1c > 0.f){ atomicAdd(&hcl[NBINS-1], (((u32)h1c)<<16) | (u32)h1l); atomicAdd(&hes[NBINS-1], h1e); }
  }
  __syncthreads();

  // merge block-local histogram to global (skip-empty)
  u64*   hp = hist + (size_t)bn*NBINS;
  float* sp = esum + (size_t)bn*NBINS;
  for(int i=tid; i<NBINS; i+=256){
    u32 v = hcl[i];
    if(v){
      atomicAdd(&hp[i], ((u64)(v>>16)<<32) | (u64)(v & 0xffffu));
      atomicAdd(&sp[i], hes[i]);
    }
  }

  // ---- last-merger-per-instance runs the lovasz scan (no threadfence:
  // atomics are coherent-point; vmcnt(0) orders this block's adds)
  asm volatile("s_waitcnt vmcnt(0)" ::: "memory");
  if(tid == 0){
    u32 old = __hip_atomic_fetch_add(&mdone[bn], 1u,
                                     __ATOMIC_RELAXED, __HIP_MEMORY_SCOPE_AGENT);
    lastFlag = (old == (u32)(NCHUNK-1));
  }
  __syncthreads();
  if(!lastFlag) return;

  {
    const int PT = NBINS/256;   // 4 bins per thread (reversed order)
    float G = red[2*E_];        // instance count, still live in LDS

    u64 loc[PT]; u64 sacc = 0;
    #pragma unroll
    for(int k=0;k<PT;k++){
      loc[k] = __hip_atomic_load(&hp[NBINS-1 - (tid*PT + k)],
                                 __ATOMIC_RELAXED, __HIP_MEMORY_SCOPE_AGENT);
      sacc += loc[k];
    }
    u64 sc = sacc;
    #pragma unroll
    for(int off=1;off<64;off<<=1){ u64 v = __shfl_up(sc, off, 64); if(lane>=off) sc += v; }
    if(lane==63) wsum[wave] = sc;
    __syncthreads();
    if(tid==0){
      u64 run = 0;
      #pragma unroll
      for(int w=0;w<4;w++){ wbase[w] = run; run += wsum[w]; }
    }
    __syncthreads();
    u64 excl = wbase[wave] + (sc - sacc);

    float lsum = 0.f;
    #pragma unroll
    for(int k=0;k<PT;k++){
      u64 lv = loc[k];
      u32 cb = (u32)(lv>>32), lb = (u32)(lv & 0xffffffffu);
      if(cb){
        float i0 = (float)(u32)(excl>>32);
        float cc0 = (float)(u32)(excl & 0xffffffffu);
        float cc1 = cc0 + (float)lb;
        float jend   = 1.f - (G - cc1)/(G + i0 + (float)cb - cc1);
        float jstart = 1.f - (G - cc0)/(G + i0 - cc0);   // i0=0,c0=0 -> 0
        float esv = __hip_atomic_load(&sp[NBINS-1 - (tid*PT + k)],
                                      __ATOMIC_RELAXED, __HIP_MEMORY_SCOPE_AGENT);
        lsum += (esv / (float)cb) * (jend - jstart);
      }
      excl += lv;
    }

    float tot = waveReduceSum(lsum);
    if(lane==0) rs[wave] = tot;
    __syncthreads();
    if(tid==0) atomicAdd(out, (rs[0]+rs[1]+rs[2]+rs[3]) * (1.0f/(float)NINST));
  }
}

extern "C" void kernel_launch(void* const* d_in, const int* in_sizes, int n_in,
                              void* d_out, int out_size, void* d_ws, size_t ws_size,
                              hipStream_t stream){
  const float* mf1 = (const float*)d_in[0];
  const float* mf2 = (const float*)d_in[1];
  const int*   gt  = (const int*)d_in[2];
  float* out = (float*)d_out;

  // ws layout: [instAcc 3456][done 96][mdone 96][pad][hist 192K][esum 96K]
  float* instAcc = (float*)d_ws;
  u32*   done    = (u32*)((char*)d_ws + 3456);
  u32*   mdone   = (u32*)((char*)d_ws + 3552);
  u64*   hist    = (u64*)((char*)d_ws + 4096);
  float* esum    = (float*)((char*)d_ws + 4096 + 196608);
  size_t zbytes  = 3648;   // instAcc + done + mdone (hist/esum zeroed in-kernel)

  hipMemsetAsync(d_ws, 0, zbytes, stream);
  k_fused<<<GRID_SWZ, 256, 0, stream>>>(mf1, mf2, gt, instAcc, done, mdone,
                                        hist, esum, out);
}

// Round 12
// 99.220 us; speedup vs baseline: 3.1924x; 2.1151x over previous
//
#include <hip/hip_runtime.h>
#include <cstdint>

#define B_ 2
#define E_ 16
#define H_ 160
#define W_ 288
#define N_ 12
#define T_ 2
#define HW_ (H_*W_)        // 46080
#define P_ (T_*HW_)        // 92160
#define NINST (B_*N_)      // 24
#define NBINS 1024         // err in [0,2] -> bin = min(1023, err*512)
#define BINSCALE 512.0f
#define CHUNK 1536         // px per block; 30 chunks/frame, 60/instance
#define NCHUNK 60
#define NGROUPS 120        // (b,chunk) groups: 2 * 60
#define GRID_SWZ 1440      // 8 xcd * 15 gslots * 12 instances (bijective, no padding)
#define PSTRIDE 36         // partial-slot stride (33 floats used)

typedef unsigned long long u64;
typedef unsigned int u32;

__device__ inline float waveReduceSum(float v){
  #pragma unroll
  for(int o=32;o>0;o>>=1) v += __shfl_down(v, o, 64);
  return v;
}

// Fold-reduction: sum v[0..15] across 64 lanes in 15+2 shuffles.
// Result: every lane holds the 64-lane sum of e = bitrev4(lane&15).
#define FOLD_STEP(m, half) \
  { bool hi = (lane & (m)) != 0; \
    _Pragma("unroll") \
    for(int i=0;i<(half);i++){ \
      float send = hi ? v[i] : v[i+(half)]; \
      float recv = __shfl_xor(send, (m), 64); \
      v[i] = (hi ? v[i+(half)] : v[i]) + recv; } }

__device__ inline float fold16sum(float* v, int lane){
  FOLD_STEP(1,8) FOLD_STEP(2,4) FOLD_STEP(4,2) FOLD_STEP(8,1)
  float r = v[0];
  r += __shfl_xor(r, 16, 64);
  r += __shfl_xor(r, 32, 64);
  return r;
}

// XCD swizzle: the 12 instance-blocks sharing one (b,chunk) emb tile are
// congruent mod 8 -> same XCD L2 (and k_err re-reads hit L2 from k_stats).
// 120 groups / 8 xcd = 15 gslots exactly -> bijective, no padding blocks.
__device__ inline void decode_blk(int lid, int& bn, int& t, int& rbase, int& y_out){
  int xcd = lid & 7, k = lid >> 3;
  int j = k % 12, gslot = k / 12;       // gslot 0..14
  int g = xcd + 8*gslot;                // 0..119
  int b = g & 1, y = g >> 1;            // y = chunk 0..59
  bn = b*N_ + j;
  t = y / 30;
  rbase = (y - t*30) * CHUNK;
  y_out = y;
}

// ---- Pass A: masked sum + sum-of-squares + count -> per-block partial slot
// (non-atomic, fully overwritten -> no pre-zero). Also zeroes hist/esum/
// mdone/out. 1536 px/block = 1 int4/float4 iter + 1 int2/float2 iter.
__global__ __launch_bounds__(256) void k_stats(const float* __restrict__ mf1,
                        const float* __restrict__ mf2,
                        const int* __restrict__ gt,
                        float* __restrict__ partial,
                        u64* __restrict__ hist, float* __restrict__ esum,
                        u32* __restrict__ mdone, float* __restrict__ out){
  int lid = blockIdx.x, tid = threadIdx.x;
  int gtid = lid*256 + tid;
  if(gtid < NINST*NBINS){ hist[gtid] = 0ull; esum[gtid] = 0.f; }
  if(gtid < NINST) mdone[gtid] = 0u;
  if(gtid == 0) *out = 0.f;

  int bn, t, rbase, y;
  decode_blk(lid, bn, t, rbase, y);
  int b = bn / N_;
  int lane = tid & 63;

  const float* ep = (t ? mf2 : mf1) + (size_t)b*(E_*HW_);
  const int*   gp = gt + ((size_t)bn*T_ + t)*HW_ + rbase;

  float s[E_], q[E_]; float c;
  { // iter A: px [0,1024)
    int off = tid*4;
    int4 m4 = *(const int4*)(gp + off);
    float m0=(float)m4.x, m1=(float)m4.y, m2=(float)m4.z, m3=(float)m4.w;
    c = m0+m1+m2+m3;
    #pragma unroll
    for(int e=0;e<E_;e++){
      float4 x = *(const float4*)(ep + (size_t)e*HW_ + rbase + off);
      float mx0=m0*x.x; float se=mx0;       float qe=mx0*x.x;
      float mx1=m1*x.y; se+=mx1; qe=fmaf(mx1,x.y,qe);
      float mx2=m2*x.z; se+=mx2; qe=fmaf(mx2,x.z,qe);
      float mx3=m3*x.w; se+=mx3; qe=fmaf(mx3,x.w,qe);
      s[e]=se; q[e]=qe;
    }
  }
  { // iter B: px [1024,1536)
    int off = 1024 + tid*2;
    int2 mm = *(const int2*)(gp + off);
    float m0=(float)mm.x, m1=(float)mm.y;
    c += m0+m1;
    #pragma unroll
    for(int e=0;e<E_;e++){
      float2 x = *(const float2*)(ep + (size_t)e*HW_ + rbase + off);
      float se=s[e], qe=q[e];
      float mx0=m0*x.x; se+=mx0; qe=fmaf(mx0,x.x,qe);
      float mx1=m1*x.y; se+=mx1; qe=fmaf(mx1,x.y,qe);
      s[e]=se; q[e]=qe;
    }
  }

  __shared__ float red[2*E_+1];
  if(tid < 2*E_+1) red[tid] = 0.f;
  __syncthreads();
  float sf = fold16sum(s, lane);
  float qf = fold16sum(q, lane);
  float cf = waveReduceSum(c);
  int ee = ((lane&1)<<3)|((lane&2)<<1)|((lane&4)>>1)|((lane&8)>>3);  // bitrev4
  if(lane < 16){
    atomicAdd(&red[ee],    sf);
    atomicAdd(&red[E_+ee], qf);
  }
  if(lane == 0) atomicAdd(&red[2*E_], cf);
  __syncthreads();
  if(tid < 2*E_+1) partial[(bn*NCHUNK + y)*PSTRIDE + tid] = red[tid];
}

// ---- Pass B: per-instance LDS histogram of (count, labelsum, errsum);
// the LAST merging block of each instance (mdone counter, NO threadfence --
// round-10-validated: vmcnt(0) + relaxed agent RMW + agent atomic loads)
// runs the descending bin scan + closed-form lovasz dot inline.
__global__ __launch_bounds__(256) void k_err(const float* __restrict__ mf1,
                                             const float* __restrict__ mf2,
                                             const int* __restrict__ gt,
                                             const float* __restrict__ partial,
                                             u64* __restrict__ hist,
                                             float* __restrict__ esum,
                                             u32* __restrict__ mdone,
                                             float* __restrict__ out){
  __shared__ u32   hcl[NBINS];   // count<<16 | labelsum (block-local, fits 16b)
  __shared__ float hes[NBINS];
  __shared__ float red[2*E_+1];
  __shared__ float pred[4][2*E_+1];
  __shared__ u64 wsum[4], wbase[4];
  __shared__ float rs[4];
  __shared__ int lastFlag;
  int bn, t, rbase, y;
  decode_blk(blockIdx.x, bn, t, rbase, y);
  int tid = threadIdx.x, lane = tid & 63, wave = tid >> 6;
  int b = bn / N_;

  // stage 1: segment sums (4 segs x 15 chunks); loads independent
  {
    int seg = wave, val = lane;
    if(val < 2*E_+1){
      float v = 0.f;
      #pragma unroll
      for(int i=0;i<15;i++)
        v += partial[(bn*NCHUNK + seg*15 + i)*PSTRIDE + val];
      pred[seg][val] = v;
    }
  }
  for(int i=tid; i<NBINS; i+=256){ hcl[i]=0u; hes[i]=0.f; }
  __syncthreads();
  // stage 2: fixed-order combine -> bit-identical across blocks of same bn
  if(tid < 2*E_+1)
    red[tid] = ((pred[0][tid] + pred[1][tid]) + pred[2][tid]) + pred[3][tid];
  __syncthreads();
  if(tid < E_){
    float cc = red[2*E_];
    float mu = red[tid] / cc;
    float vv = (red[E_+tid] - cc*mu*mu) / (cc - 1.0f);
    red[tid] = mu; red[E_+tid] = vv;   // thread e only touches e, 16+e; red[32] kept
  }
  __syncthreads();
  float mn[E_], sv[E_];
  #pragma unroll
  for(int e=0;e<E_;e++){ mn[e]=red[e]; sv[e]=red[E_+e]; }

  const float* ep = (t ? mf2 : mf1) + (size_t)b*(E_*HW_);
  const int*   gp = gt + ((size_t)bn*T_ + t)*HW_ + rbase;

  float h0c=0.f,h0l=0.f,h0e=0.f, h1c=0.f,h1l=0.f,h1e=0.f;
  auto proc = [&](float d, int mi){
    float logits = 2.f*__expf(-0.5f*d) - 1.f;
    float ev = fmaxf(1.f - logits*(2.f*(float)mi - 1.f), 0.f);   // in [0,2]
    int bin = min(NBINS-1, (int)(ev * BINSCALE));
    if(bin == 0)            { h0c+=1.f; h0l+=(float)mi; h0e+=ev; }
    else if(bin == NBINS-1) { h1c+=1.f; h1l+=(float)mi; h1e+=ev; }
    else {
      atomicAdd(&hcl[bin], 0x10000u | (u32)mi);
      atomicAdd(&hes[bin], ev);
    }
  };

  { // iter A: px [0,1024)
    int off = tid*4;
    int4 m4 = *(const int4*)(gp + off);
    float d0=0.f,d1=0.f,d2=0.f,d3=0.f;
    #pragma unroll
    for(int e=0;e<E_;e++){
      float4 x = *(const float4*)(ep + (size_t)e*HW_ + rbase + off);
      float mne=mn[e], sve=sv[e];
      float f0=x.x-mne; d0=fmaf(f0*f0, sve, d0);
      float f1=x.y-mne; d1=fmaf(f1*f1, sve, d1);
      float f2=x.z-mne; d2=fmaf(f2*f2, sve, d2);
      float f3=x.w-mne; d3=fmaf(f3*f3, sve, d3);
    }
    proc(d0,m4.x); proc(d1,m4.y); proc(d2,m4.z); proc(d3,m4.w);
  }
  { // iter B: px [1024,1536)
    int off = 1024 + tid*2;
    int2 mm = *(const int2*)(gp + off);
    float d0=0.f,d1=0.f;
    #pragma unroll
    for(int e=0;e<E_;e++){
      float2 x = *(const float2*)(ep + (size_t)e*HW_ + rbase + off);
      float mne=mn[e], sve=sv[e];
      float f0=x.x-mne; d0=fmaf(f0*f0, sve, d0);
      float f1=x.y-mne; d1=fmaf(f1*f1, sve, d1);
    }
    proc(d0,mm.x); proc(d1,mm.y);
  }

  // flush hot-bin registers (one wave-reduce, 4 LDS atomics per wave)
  h0c = waveReduceSum(h0c); h0l = waveReduceSum(h0l); h0e = waveReduceSum(h0e);
  h1c = waveReduceSum(h1c); h1l = waveReduceSum(h1l); h1e = waveReduceSum(h1e);
  if(lane == 0){
    if(h0c > 0.f){ atomicAdd(&hcl[0],       (((u32)h0c)<<16) | (u32)h0l); atomicAdd(&hes[0],       h0e); }
    if(h1c > 0.f){ atomicAdd(&hcl[NBINS-1], (((u32)h1c)<<16) | (u32)h1l); atomicAdd(&hes[NBINS-1], h1e); }
  }
  __syncthreads();

  u64*   hp = hist + (size_t)bn*NBINS;
  float* sp = esum + (size_t)bn*NBINS;
  for(int i=tid; i<NBINS; i+=256){
    u32 v = hcl[i];
    if(v){
      atomicAdd(&hp[i], ((u64)(v>>16)<<32) | (u64)(v & 0xffffu));
      atomicAdd(&sp[i], hes[i]);
    }
  }

  // ---- last-merger-per-instance runs the lovasz scan.
  // NO __threadfence (round-4 lesson); ordering = vmcnt(0) drains this
  // block's device-scope atomics (coherent point) before the mdone RMW.
  asm volatile("s_waitcnt vmcnt(0)" ::: "memory");
  if(tid == 0){
    u32 old = __hip_atomic_fetch_add(&mdone[bn], 1u,
                                     __ATOMIC_RELAXED, __HIP_MEMORY_SCOPE_AGENT);
    lastFlag = (old == (u32)(NCHUNK-1));
  }
  __syncthreads();
  if(!lastFlag) return;

  {
    const int PT = NBINS/256;   // 4 bins per thread (reversed order)
    float G = red[2*E_];        // instance count, still live in LDS

    u64 loc[PT]; u64 s = 0;
    #pragma unroll
    for(int k=0;k<PT;k++){
      loc[k] = __hip_atomic_load(&hp[NBINS-1 - (tid*PT + k)],
                                 __ATOMIC_RELAXED, __HIP_MEMORY_SCOPE_AGENT);
      s += loc[k];
    }
    u64 sc = s;
    #pragma unroll
    for(int off=1;off<64;off<<=1){ u64 v = __shfl_up(sc, off, 64); if(lane>=off) sc += v; }
    if(lane==63) wsum[wave] = sc;
    __syncthreads();
    if(tid==0){
      u64 run = 0;
      #pragma unroll
      for(int w=0;w<4;w++){ wbase[w] = run; run += wsum[w]; }
    }
    __syncthreads();
    u64 excl = wbase[wave] + (sc - s);

    float lsum = 0.f;
    #pragma unroll
    for(int k=0;k<PT;k++){
      u64 lv = loc[k];
      u32 cb = (u32)(lv>>32), lb = (u32)(lv & 0xffffffffu);
      if(cb){
        float i0 = (float)(u32)(excl>>32);
        float c0 = (float)(u32)(excl & 0xffffffffu);
        float c1 = c0 + (float)lb;
        float jend   = 1.f - (G - c1)/(G + i0 + (float)cb - c1);
        float jstart = 1.f - (G - c0)/(G + i0 - c0);   // i0=0,c0=0 -> 0
        float esv = __hip_atomic_load(&sp[NBINS-1 - (tid*PT + k)],
                                      __ATOMIC_RELAXED, __HIP_MEMORY_SCOPE_AGENT);
        lsum += (esv / (float)cb) * (jend - jstart);
      }
      excl += lv;
    }

    float tot = waveReduceSum(lsum);
    if(lane==0) rs[wave] = tot;
    __syncthreads();
    if(tid==0) atomicAdd(out, (rs[0]+rs[1]+rs[2]+rs[3]) * (1.0f/(float)NINST));
  }
}

extern "C" void kernel_launch(void* const* d_in, const int* in_sizes, int n_in,
                              void* d_out, int out_size, void* d_ws, size_t ws_size,
                              hipStream_t stream){
  const float* mf1 = (const float*)d_in[0];
  const float* mf2 = (const float*)d_in[1];
  const int*   gt  = (const int*)d_in[2];
  float* out = (float*)d_out;

  // ws layout
  u64*   hist    = (u64*)d_ws;                                      // 192 KB
  float* esum    = (float*)((char*)d_ws + 196608);                  // 96 KB
  float* partial = (float*)((char*)d_ws + 294912);                  // 203 KB
  u32*   mdone   = (u32*)((char*)d_ws + 507904);                    // 96 B

  k_stats<<<GRID_SWZ, 256, 0, stream>>>(mf1, mf2, gt, partial, hist, esum, mdone, out);
  k_err  <<<GRID_SWZ, 256, 0, stream>>>(mf1, mf2, gt, partial, hist, esum, mdone, out);
}

// Round 13
// 92.993 us; speedup vs baseline: 3.4062x; 1.0670x over previous
//
#include <hip/hip_runtime.h>
#include <cstdint>

#define B_ 2
#define E_ 16
#define H_ 160
#define W_ 288
#define N_ 12
#define T_ 2
#define HW_ (H_*W_)        // 46080
#define P_ (T_*HW_)        // 92160
#define NINST (B_*N_)      // 24
#define NBINS 512          // err in [0,2] -> bin = min(511, err*256)
#define BINSCALE 256.0f
#define CHUNK 1536         // px per block; 30 chunks/frame, 60/instance
#define NCHUNK 60
#define NGROUPS 120        // (b,chunk) groups: 2 * 60
#define GRID_SWZ 1440      // 8 xcd * 15 gslots * 12 instances (bijective, no padding)
#define PSTRIDE 36         // partial-slot stride (33 floats used)

typedef unsigned long long u64;
typedef unsigned int u32;

__device__ inline float waveReduceSum(float v){
  #pragma unroll
  for(int o=32;o>0;o>>=1) v += __shfl_down(v, o, 64);
  return v;
}

// Fold-reduction: sum v[0..15] across 64 lanes in 15+2 shuffles.
// Result: every lane holds the 64-lane sum of e = bitrev4(lane&15).
#define FOLD_STEP(m, half) \
  { bool hi = (lane & (m)) != 0; \
    _Pragma("unroll") \
    for(int i=0;i<(half);i++){ \
      float send = hi ? v[i] : v[i+(half)]; \
      float recv = __shfl_xor(send, (m), 64); \
      v[i] = (hi ? v[i+(half)] : v[i]) + recv; } }

__device__ inline float fold16sum(float* v, int lane){
  FOLD_STEP(1,8) FOLD_STEP(2,4) FOLD_STEP(4,2) FOLD_STEP(8,1)
  float r = v[0];
  r += __shfl_xor(r, 16, 64);
  r += __shfl_xor(r, 32, 64);
  return r;
}

// XCD swizzle: the 12 instance-blocks sharing one (b,chunk) emb tile are
// congruent mod 8 -> same XCD L2 (and k_err re-reads hit L2 from k_stats).
// 120 groups / 8 xcd = 15 gslots exactly -> bijective, no padding blocks.
__device__ inline void decode_blk(int lid, int& bn, int& t, int& rbase, int& y_out){
  int xcd = lid & 7, k = lid >> 3;
  int j = k % 12, gslot = k / 12;       // gslot 0..14
  int g = xcd + 8*gslot;                // 0..119
  int b = g & 1, y = g >> 1;            // y = chunk 0..59
  bn = b*N_ + j;
  t = y / 30;
  rbase = (y - t*30) * CHUNK;
  y_out = y;
}

// ---- Pass A: masked sum + sum-of-squares + count -> per-block partial slot
// (non-atomic, fully overwritten -> no pre-zero). Also zeroes hist/esum/out.
// 1536 px/block = 1 int4/float4 iter (1024) + 1 int2/float2 iter (512).
__global__ __launch_bounds__(256) void k_stats(const float* __restrict__ mf1,
                        const float* __restrict__ mf2,
                        const int* __restrict__ gt,
                        float* __restrict__ partial,
                        u64* __restrict__ hist, float* __restrict__ esum,
                        float* __restrict__ out){
  int lid = blockIdx.x, tid = threadIdx.x;
  int gtid = lid*256 + tid;
  if(gtid < NINST*NBINS){ hist[gtid] = 0ull; esum[gtid] = 0.f; }
  if(gtid == 0) *out = 0.f;

  int bn, t, rbase, y;
  decode_blk(lid, bn, t, rbase, y);
  int b = bn / N_;
  int lane = tid & 63;

  const float* ep = (t ? mf2 : mf1) + (size_t)b*(E_*HW_);
  const int*   gp = gt + ((size_t)bn*T_ + t)*HW_ + rbase;

  float s[E_], q[E_]; float c;
  { // iter A: px [0,1024)
    int off = tid*4;
    int4 m4 = *(const int4*)(gp + off);
    float m0=(float)m4.x, m1=(float)m4.y, m2=(float)m4.z, m3=(float)m4.w;
    c = m0+m1+m2+m3;
    #pragma unroll
    for(int e=0;e<E_;e++){
      float4 x = *(const float4*)(ep + (size_t)e*HW_ + rbase + off);
      float mx0=m0*x.x; float se=mx0;       float qe=mx0*x.x;
      float mx1=m1*x.y; se+=mx1; qe=fmaf(mx1,x.y,qe);
      float mx2=m2*x.z; se+=mx2; qe=fmaf(mx2,x.z,qe);
      float mx3=m3*x.w; se+=mx3; qe=fmaf(mx3,x.w,qe);
      s[e]=se; q[e]=qe;
    }
  }
  { // iter B: px [1024,1536)
    int off = 1024 + tid*2;
    int2 mm = *(const int2*)(gp + off);
    float m0=(float)mm.x, m1=(float)mm.y;
    c += m0+m1;
    #pragma unroll
    for(int e=0;e<E_;e++){
      float2 x = *(const float2*)(ep + (size_t)e*HW_ + rbase + off);
      float se=s[e], qe=q[e];
      float mx0=m0*x.x; se+=mx0; qe=fmaf(mx0,x.x,qe);
      float mx1=m1*x.y; se+=mx1; qe=fmaf(mx1,x.y,qe);
      s[e]=se; q[e]=qe;
    }
  }

  __shared__ float red[2*E_+1];
  if(tid < 2*E_+1) red[tid] = 0.f;
  __syncthreads();
  float sf = fold16sum(s, lane);
  float qf = fold16sum(q, lane);
  float cf = waveReduceSum(c);
  int ee = ((lane&1)<<3)|((lane&2)<<1)|((lane&4)>>1)|((lane&8)>>3);  // bitrev4
  if(lane < 16){
    atomicAdd(&red[ee],    sf);
    atomicAdd(&red[E_+ee], qf);
  }
  if(lane == 0) atomicAdd(&red[2*E_], cf);
  __syncthreads();
  if(tid < 2*E_+1) partial[(bn*NCHUNK + y)*PSTRIDE + tid] = red[tid];
}

// ---- Pass B: per-instance LDS histogram of (count, labelsum, errsum).
// mean/var recomputed per block from partials (4 segs x 15 independent loads;
// fixed combine order -> bit-identical across blocks of an instance).
// gt re-read directly (L2-hot under the XCD swizzle). Bins 0 / NBINS-1
// (~50% of px) accumulate in registers -> no LDS-atomic hotspots.
__global__ __launch_bounds__(256) void k_err(const float* __restrict__ mf1,
                                             const float* __restrict__ mf2,
                                             const int* __restrict__ gt,
                                             const float* __restrict__ partial,
                                             u64* __restrict__ hist,
                                             float* __restrict__ esum){
  __shared__ u32   hcl[NBINS];   // count<<16 | labelsum (block-local, fits 16b)
  __shared__ float hes[NBINS];
  __shared__ float red[2*E_+1];
  __shared__ float pred[4][2*E_+1];
  int bn, t, rbase, y;
  decode_blk(blockIdx.x, bn, t, rbase, y);
  int tid = threadIdx.x, lane = tid & 63, wave = tid >> 6;
  int b = bn / N_;

  // stage 1: segment sums (4 segs x 15 chunks); loads independent
  {
    int seg = wave, val = lane;
    if(val < 2*E_+1){
      float v = 0.f;
      #pragma unroll
      for(int i=0;i<15;i++)
        v += partial[(bn*NCHUNK + seg*15 + i)*PSTRIDE + val];
      pred[seg][val] = v;
    }
  }
  for(int i=tid; i<NBINS; i+=256){ hcl[i]=0u; hes[i]=0.f; }
  __syncthreads();
  // stage 2: fixed-order combine -> bit-identical across blocks of same bn
  if(tid < 2*E_+1)
    red[tid] = ((pred[0][tid] + pred[1][tid]) + pred[2][tid]) + pred[3][tid];
  __syncthreads();
  if(tid < E_){
    float cc = red[2*E_];
    float mu = red[tid] / cc;
    float vv = (red[E_+tid] - cc*mu*mu) / (cc - 1.0f);
    red[tid] = mu; red[E_+tid] = vv;   // thread e only touches e, 16+e
  }
  __syncthreads();
  float mn[E_], sv[E_];
  #pragma unroll
  for(int e=0;e<E_;e++){ mn[e]=red[e]; sv[e]=red[E_+e]; }

  const float* ep = (t ? mf2 : mf1) + (size_t)b*(E_*HW_);
  const int*   gp = gt + ((size_t)bn*T_ + t)*HW_ + rbase;

  float h0c=0.f,h0l=0.f,h0e=0.f, h1c=0.f,h1l=0.f,h1e=0.f;
  auto proc = [&](float d, int mi){
    float logits = 2.f*__expf(-0.5f*d) - 1.f;
    float ev = fmaxf(1.f - logits*(2.f*(float)mi - 1.f), 0.f);   // in [0,2]
    int bin = min(NBINS-1, (int)(ev * BINSCALE));
    if(bin == 0)            { h0c+=1.f; h0l+=(float)mi; h0e+=ev; }
    else if(bin == NBINS-1) { h1c+=1.f; h1l+=(float)mi; h1e+=ev; }
    else {
      atomicAdd(&hcl[bin], 0x10000u | (u32)mi);
      atomicAdd(&hes[bin], ev);
    }
  };

  { // iter A: px [0,1024)
    int off = tid*4;
    int4 m4 = *(const int4*)(gp + off);
    float d0=0.f,d1=0.f,d2=0.f,d3=0.f;
    #pragma unroll
    for(int e=0;e<E_;e++){
      float4 x = *(const float4*)(ep + (size_t)e*HW_ + rbase + off);
      float mne=mn[e], sve=sv[e];
      float f0=x.x-mne; d0=fmaf(f0*f0, sve, d0);
      float f1=x.y-mne; d1=fmaf(f1*f1, sve, d1);
      float f2=x.z-mne; d2=fmaf(f2*f2, sve, d2);
      float f3=x.w-mne; d3=fmaf(f3*f3, sve, d3);
    }
    proc(d0,m4.x); proc(d1,m4.y); proc(d2,m4.z); proc(d3,m4.w);
  }
  { // iter B: px [1024,1536)
    int off = 1024 + tid*2;
    int2 mm = *(const int2*)(gp + off);
    float d0=0.f,d1=0.f;
    #pragma unroll
    for(int e=0;e<E_;e++){
      float2 x = *(const float2*)(ep + (size_t)e*HW_ + rbase + off);
      float mne=mn[e], sve=sv[e];
      float f0=x.x-mne; d0=fmaf(f0*f0, sve, d0);
      float f1=x.y-mne; d1=fmaf(f1*f1, sve, d1);
    }
    proc(d0,mm.x); proc(d1,mm.y);
  }

  // flush hot-bin registers (one wave-reduce, 4 LDS atomics per wave)
  h0c = waveReduceSum(h0c); h0l = waveReduceSum(h0l); h0e = waveReduceSum(h0e);
  h1c = waveReduceSum(h1c); h1l = waveReduceSum(h1l); h1e = waveReduceSum(h1e);
  if(lane == 0){
    if(h0c > 0.f){ atomicAdd(&hcl[0],       (((u32)h0c)<<16) | (u32)h0l); atomicAdd(&hes[0],       h0e); }
    if(h1c > 0.f){ atomicAdd(&hcl[NBINS-1], (((u32)h1c)<<16) | (u32)h1l); atomicAdd(&hes[NBINS-1], h1e); }
  }
  __syncthreads();

  u64*   hp = hist + (size_t)bn*NBINS;
  float* sp = esum + (size_t)bn*NBINS;
  for(int i=tid; i<NBINS; i+=256){
    u32 v = hcl[i];
    if(v){
      atomicAdd(&hp[i], ((u64)(v>>16)<<32) | (u64)(v & 0xffffu));
      atomicAdd(&sp[i], hes[i]);
    }
  }
}

// ---- Pass C: per-instance descending bin scan + closed-form lovasz dot.
__global__ __launch_bounds__(256) void k_bins(const u64* __restrict__ hist,
                                              const float* __restrict__ esum,
                                              const float* __restrict__ partial,
                                              float* __restrict__ out){
  const int PT = NBINS/256;   // 2 bins per thread (reversed order)
  int bn = blockIdx.x;
  const u64*   h  = hist + (size_t)bn*NBINS;
  const float* es = esum + (size_t)bn*NBINS;
  int tid = threadIdx.x, lane = tid & 63, wave = tid >> 6;

  __shared__ float Gs;
  // parallel G: counts are integer-valued floats -> any sum order is exact
  if(wave == 0){
    float gv = (lane < NCHUNK) ? partial[(bn*NCHUNK + lane)*PSTRIDE + 2*E_] : 0.f;
    gv = waveReduceSum(gv);
    if(lane == 0) Gs = gv;
  }

  u64 loc[PT]; u64 s = 0;
  #pragma unroll
  for(int k=0;k<PT;k++){
    loc[k] = h[NBINS-1 - (tid*PT + k)];
    s += loc[k];
  }
  u64 sc = s;
  #pragma unroll
  for(int off=1;off<64;off<<=1){ u64 v = __shfl_up(sc, off, 64); if(lane>=off) sc += v; }
  __shared__ u64 wsum[4], wbase[4];
  if(lane==63) wsum[wave] = sc;
  __syncthreads();
  if(tid==0){
    u64 run = 0;
    #pragma unroll
    for(int w=0;w<4;w++){ wbase[w] = run; run += wsum[w]; }
  }
  __syncthreads();
  u64 excl = wbase[wave] + (sc - s);

  float G = Gs;
  float lsum = 0.f;
  #pragma unroll
  for(int k=0;k<PT;k++){
    u64 lv = loc[k];
    u32 cb = (u32)(lv>>32), lb = (u32)(lv & 0xffffffffu);
    if(cb){
      float i0 = (float)(u32)(excl>>32);
      float c0 = (float)(u32)(excl & 0xffffffffu);
      float c1 = c0 + (float)lb;
      float jend   = 1.f - (G - c1)/(G + i0 + (float)cb - c1);
      float jstart = 1.f - (G - c0)/(G + i0 - c0);   // i0=0,c0=0 -> 0
      lsum += (es[NBINS-1 - (tid*PT + k)] / (float)cb) * (jend - jstart);
    }
    excl += lv;
  }

  __shared__ float rs[4];
  float tot = waveReduceSum(lsum);
  if(lane==0) rs[wave] = tot;
  __syncthreads();
  if(tid==0) atomicAdd(out, (rs[0]+rs[1]+rs[2]+rs[3]) * (1.0f/(float)NINST));
}

extern "C" void kernel_launch(void* const* d_in, const int* in_sizes, int n_in,
                              void* d_out, int out_size, void* d_ws, size_t ws_size,
                              hipStream_t stream){
  const float* mf1 = (const float*)d_in[0];
  const float* mf2 = (const float*)d_in[1];
  const int*   gt  = (const int*)d_in[2];
  float* out = (float*)d_out;

  // ws layout
  u64*   hist    = (u64*)d_ws;                                      // 24*512*8 = 96 KB
  float* esum    = (float*)((char*)d_ws + 98304);                   // 48 KB
  float* partial = (float*)((char*)d_ws + 147456);                  // 203 KB

  k_stats<<<GRID_SWZ, 256, 0, stream>>>(mf1, mf2, gt, partial, hist, esum, out);
  k_err  <<<GRID_SWZ, 256, 0, stream>>>(mf1, mf2, gt, partial, hist, esum);
  k_bins <<<NINST, 256, 0, stream>>>(hist, esum, partial, out);
}

// Round 14
// 91.161 us; speedup vs baseline: 3.4746x; 1.0201x over previous
//
#include <hip/hip_runtime.h>
#include <cstdint>

#define B_ 2
#define E_ 16
#define H_ 160
#define W_ 288
#define N_ 12
#define T_ 2
#define HW_ (H_*W_)        // 46080
#define P_ (T_*HW_)        // 92160
#define NINST (B_*N_)      // 24
#define NBINS 256          // err in [0,2] -> bin = min(255, err*128)
#define BINSCALE 128.0f
#define CHUNK 1536         // px per block; 30 chunks/frame, 60/instance
#define NCHUNK 60
#define NGROUPS 120        // (b,chunk) groups: 2 * 60
#define GRID_SWZ 1440      // 8 xcd * 15 gslots * 12 instances (bijective, no padding)
#define PSTRIDE 36         // partial-slot stride (33 floats used)

typedef unsigned long long u64;
typedef unsigned int u32;

__device__ inline float waveReduceSum(float v){
  #pragma unroll
  for(int o=32;o>0;o>>=1) v += __shfl_down(v, o, 64);
  return v;
}

// Fold-reduction: sum v[0..15] across 64 lanes in 15+2 shuffles.
// Result: every lane holds the 64-lane sum of e = bitrev4(lane&15).
#define FOLD_STEP(m, half) \
  { bool hi = (lane & (m)) != 0; \
    _Pragma("unroll") \
    for(int i=0;i<(half);i++){ \
      float send = hi ? v[i] : v[i+(half)]; \
      float recv = __shfl_xor(send, (m), 64); \
      v[i] = (hi ? v[i+(half)] : v[i]) + recv; } }

__device__ inline float fold16sum(float* v, int lane){
  FOLD_STEP(1,8) FOLD_STEP(2,4) FOLD_STEP(4,2) FOLD_STEP(8,1)
  float r = v[0];
  r += __shfl_xor(r, 16, 64);
  r += __shfl_xor(r, 32, 64);
  return r;
}

// XCD swizzle: the 12 instance-blocks sharing one (b,chunk) emb tile are
// congruent mod 8 -> same XCD L2 (and k_err re-reads hit L2 from k_stats).
// 120 groups / 8 xcd = 15 gslots exactly -> bijective, no padding blocks.
__device__ inline void decode_blk(int lid, int& bn, int& t, int& rbase, int& y_out){
  int xcd = lid & 7, k = lid >> 3;
  int j = k % 12, gslot = k / 12;       // gslot 0..14
  int g = xcd + 8*gslot;                // 0..119
  int b = g & 1, y = g >> 1;            // y = chunk 0..59
  bn = b*N_ + j;
  t = y / 30;
  rbase = (y - t*30) * CHUNK;
  y_out = y;
}

// ---- Pass A: masked sum + sum-of-squares + count -> per-block partial slot
// (non-atomic, fully overwritten -> no pre-zero). Also zeroes hist/esum/out.
// 1536 px/block = 1 int4/float4 iter (1024) + 1 int2/float2 iter (512).
__global__ __launch_bounds__(256) void k_stats(const float* __restrict__ mf1,
                        const float* __restrict__ mf2,
                        const int* __restrict__ gt,
                        float* __restrict__ partial,
                        u64* __restrict__ hist, float* __restrict__ esum,
                        float* __restrict__ out){
  int lid = blockIdx.x, tid = threadIdx.x;
  int gtid = lid*256 + tid;
  if(gtid < NINST*NBINS){ hist[gtid] = 0ull; esum[gtid] = 0.f; }
  if(gtid == 0) *out = 0.f;

  int bn, t, rbase, y;
  decode_blk(lid, bn, t, rbase, y);
  int b = bn / N_;
  int lane = tid & 63;

  const float* ep = (t ? mf2 : mf1) + (size_t)b*(E_*HW_);
  const int*   gp = gt + ((size_t)bn*T_ + t)*HW_ + rbase;

  float s[E_], q[E_]; float c;
  { // iter A: px [0,1024)
    int off = tid*4;
    int4 m4 = *(const int4*)(gp + off);
    float m0=(float)m4.x, m1=(float)m4.y, m2=(float)m4.z, m3=(float)m4.w;
    c = m0+m1+m2+m3;
    #pragma unroll
    for(int e=0;e<E_;e++){
      float4 x = *(const float4*)(ep + (size_t)e*HW_ + rbase + off);
      float mx0=m0*x.x; float se=mx0;       float qe=mx0*x.x;
      float mx1=m1*x.y; se+=mx1; qe=fmaf(mx1,x.y,qe);
      float mx2=m2*x.z; se+=mx2; qe=fmaf(mx2,x.z,qe);
      float mx3=m3*x.w; se+=mx3; qe=fmaf(mx3,x.w,qe);
      s[e]=se; q[e]=qe;
    }
  }
  { // iter B: px [1024,1536)
    int off = 1024 + tid*2;
    int2 mm = *(const int2*)(gp + off);
    float m0=(float)mm.x, m1=(float)mm.y;
    c += m0+m1;
    #pragma unroll
    for(int e=0;e<E_;e++){
      float2 x = *(const float2*)(ep + (size_t)e*HW_ + rbase + off);
      float se=s[e], qe=q[e];
      float mx0=m0*x.x; se+=mx0; qe=fmaf(mx0,x.x,qe);
      float mx1=m1*x.y; se+=mx1; qe=fmaf(mx1,x.y,qe);
      s[e]=se; q[e]=qe;
    }
  }

  __shared__ float red[2*E_+1];
  if(tid < 2*E_+1) red[tid] = 0.f;
  __syncthreads();
  float sf = fold16sum(s, lane);
  float qf = fold16sum(q, lane);
  float cf = waveReduceSum(c);
  int ee = ((lane&1)<<3)|((lane&2)<<1)|((lane&4)>>1)|((lane&8)>>3);  // bitrev4
  if(lane < 16){
    atomicAdd(&red[ee],    sf);
    atomicAdd(&red[E_+ee], qf);
  }
  if(lane == 0) atomicAdd(&red[2*E_], cf);
  __syncthreads();
  if(tid < 2*E_+1) partial[(bn*NCHUNK + y)*PSTRIDE + tid] = red[tid];
}

// ---- Pass B: per-instance LDS histogram of (count, labelsum, errsum).
// mean/var recomputed per block from partials (4 segs x 15 independent loads;
// fixed combine order -> bit-identical across blocks of an instance).
// gt re-read directly (L2-hot under the XCD swizzle). Bins 0 / NBINS-1
// (~50% of px) accumulate in registers -> no LDS-atomic hotspots.
__global__ __launch_bounds__(256) void k_err(const float* __restrict__ mf1,
                                             const float* __restrict__ mf2,
                                             const int* __restrict__ gt,
                                             const float* __restrict__ partial,
                                             u64* __restrict__ hist,
                                             float* __restrict__ esum){
  __shared__ u32   hcl[NBINS];   // count<<16 | labelsum (block-local, fits 16b)
  __shared__ float hes[NBINS];
  __shared__ float red[2*E_+1];
  __shared__ float pred[4][2*E_+1];
  int bn, t, rbase, y;
  decode_blk(blockIdx.x, bn, t, rbase, y);
  int tid = threadIdx.x, lane = tid & 63, wave = tid >> 6;
  int b = bn / N_;

  // stage 1: segment sums (4 segs x 15 chunks); loads independent
  {
    int seg = wave, val = lane;
    if(val < 2*E_+1){
      float v = 0.f;
      #pragma unroll
      for(int i=0;i<15;i++)
        v += partial[(bn*NCHUNK + seg*15 + i)*PSTRIDE + val];
      pred[seg][val] = v;
    }
  }
  if(tid < NBINS){ hcl[tid]=0u; hes[tid]=0.f; }
  __syncthreads();
  // stage 2: fixed-order combine -> bit-identical across blocks of same bn
  if(tid < 2*E_+1)
    red[tid] = ((pred[0][tid] + pred[1][tid]) + pred[2][tid]) + pred[3][tid];
  __syncthreads();
  if(tid < E_){
    float cc = red[2*E_];
    float mu = red[tid] / cc;
    float vv = (red[E_+tid] - cc*mu*mu) / (cc - 1.0f);
    red[tid] = mu; red[E_+tid] = vv;   // thread e only touches e, 16+e
  }
  __syncthreads();
  float mn[E_], sv[E_];
  #pragma unroll
  for(int e=0;e<E_;e++){ mn[e]=red[e]; sv[e]=red[E_+e]; }

  const float* ep = (t ? mf2 : mf1) + (size_t)b*(E_*HW_);
  const int*   gp = gt + ((size_t)bn*T_ + t)*HW_ + rbase;

  float h0c=0.f,h0l=0.f,h0e=0.f, h1c=0.f,h1l=0.f,h1e=0.f;
  auto proc = [&](float d, int mi){
    float logits = 2.f*__expf(-0.5f*d) - 1.f;
    float ev = fmaxf(1.f - logits*(2.f*(float)mi - 1.f), 0.f);   // in [0,2]
    int bin = min(NBINS-1, (int)(ev * BINSCALE));
    if(bin == 0)            { h0c+=1.f; h0l+=(float)mi; h0e+=ev; }
    else if(bin == NBINS-1) { h1c+=1.f; h1l+=(float)mi; h1e+=ev; }
    else {
      atomicAdd(&hcl[bin], 0x10000u | (u32)mi);
      atomicAdd(&hes[bin], ev);
    }
  };

  { // iter A: px [0,1024)
    int off = tid*4;
    int4 m4 = *(const int4*)(gp + off);
    float d0=0.f,d1=0.f,d2=0.f,d3=0.f;
    #pragma unroll
    for(int e=0;e<E_;e++){
      float4 x = *(const float4*)(ep + (size_t)e*HW_ + rbase + off);
      float mne=mn[e], sve=sv[e];
      float f0=x.x-mne; d0=fmaf(f0*f0, sve, d0);
      float f1=x.y-mne; d1=fmaf(f1*f1, sve, d1);
      float f2=x.z-mne; d2=fmaf(f2*f2, sve, d2);
      float f3=x.w-mne; d3=fmaf(f3*f3, sve, d3);
    }
    proc(d0,m4.x); proc(d1,m4.y); proc(d2,m4.z); proc(d3,m4.w);
  }
  { // iter B: px [1024,1536)
    int off = 1024 + tid*2;
    int2 mm = *(const int2*)(gp + off);
    float d0=0.f,d1=0.f;
    #pragma unroll
    for(int e=0;e<E_;e++){
      float2 x = *(const float2*)(ep + (size_t)e*HW_ + rbase + off);
      float mne=mn[e], sve=sv[e];
      float f0=x.x-mne; d0=fmaf(f0*f0, sve, d0);
      float f1=x.y-mne; d1=fmaf(f1*f1, sve, d1);
    }
    proc(d0,mm.x); proc(d1,mm.y);
  }

  // flush hot-bin registers (one wave-reduce, 4 LDS atomics per wave)
  h0c = waveReduceSum(h0c); h0l = waveReduceSum(h0l); h0e = waveReduceSum(h0e);
  h1c = waveReduceSum(h1c); h1l = waveReduceSum(h1l); h1e = waveReduceSum(h1e);
  if(lane == 0){
    if(h0c > 0.f){ atomicAdd(&hcl[0],       (((u32)h0c)<<16) | (u32)h0l); atomicAdd(&hes[0],       h0e); }
    if(h1c > 0.f){ atomicAdd(&hcl[NBINS-1], (((u32)h1c)<<16) | (u32)h1l); atomicAdd(&hes[NBINS-1], h1e); }
  }
  __syncthreads();

  u64*   hp = hist + (size_t)bn*NBINS;
  float* sp = esum + (size_t)bn*NBINS;
  if(tid < NBINS){
    u32 v = hcl[tid];
    if(v){
      atomicAdd(&hp[tid], ((u64)(v>>16)<<32) | (u64)(v & 0xffffu));
      atomicAdd(&sp[tid], hes[tid]);
    }
  }
}

// ---- Pass C: per-instance descending bin scan + closed-form lovasz dot.
__global__ __launch_bounds__(256) void k_bins(const u64* __restrict__ hist,
                                              const float* __restrict__ esum,
                                              const float* __restrict__ partial,
                                              float* __restrict__ out){
  int bn = blockIdx.x;
  const u64*   h  = hist + (size_t)bn*NBINS;
  const float* es = esum + (size_t)bn*NBINS;
  int tid = threadIdx.x, lane = tid & 63, wave = tid >> 6;

  __shared__ float Gs;
  // parallel G: counts are integer-valued floats -> any sum order is exact
  if(wave == 0){
    float gv = (lane < NCHUNK) ? partial[(bn*NCHUNK + lane)*PSTRIDE + 2*E_] : 0.f;
    gv = waveReduceSum(gv);
    if(lane == 0) Gs = gv;
  }

  // 1 bin per thread (reversed order)
  u64 s = h[NBINS-1 - tid];
  u64 sc = s;
  #pragma unroll
  for(int off=1;off<64;off<<=1){ u64 v = __shfl_up(sc, off, 64); if(lane>=off) sc += v; }
  __shared__ u64 wsum[4], wbase[4];
  if(lane==63) wsum[wave] = sc;
  __syncthreads();
  if(tid==0){
    u64 run = 0;
    #pragma unroll
    for(int w=0;w<4;w++){ wbase[w] = run; run += wsum[w]; }
  }
  __syncthreads();
  u64 excl = wbase[wave] + (sc - s);

  float G = Gs;
  float lsum = 0.f;
  {
    u64 lv = s;
    u32 cb = (u32)(lv>>32), lb = (u32)(lv & 0xffffffffu);
    if(cb){
      float i0 = (float)(u32)(excl>>32);
      float c0 = (float)(u32)(excl & 0xffffffffu);
      float c1 = c0 + (float)lb;
      float jend   = 1.f - (G - c1)/(G + i0 + (float)cb - c1);
      float jstart = 1.f - (G - c0)/(G + i0 - c0);   // i0=0,c0=0 -> 0
      lsum = (es[NBINS-1 - tid] / (float)cb) * (jend - jstart);
    }
  }

  __shared__ float rs[4];
  float tot = waveReduceSum(lsum);
  if(lane==0) rs[wave] = tot;
  __syncthreads();
  if(tid==0) atomicAdd(out, (rs[0]+rs[1]+rs[2]+rs[3]) * (1.0f/(float)NINST));
}

extern "C" void kernel_launch(void* const* d_in, const int* in_sizes, int n_in,
                              void* d_out, int out_size, void* d_ws, size_t ws_size,
                              hipStream_t stream){
  const float* mf1 = (const float*)d_in[0];
  const float* mf2 = (const float*)d_in[1];
  const int*   gt  = (const int*)d_in[2];
  float* out = (float*)d_out;

  // ws layout
  u64*   hist    = (u64*)d_ws;                                      // 24*256*8 = 48 KB
  float* esum    = (float*)((char*)d_ws + 49152);                   // 24 KB
  float* partial = (float*)((char*)d_ws + 73728);                   // 203 KB

  k_stats<<<GRID_SWZ, 256, 0, stream>>>(mf1, mf2, gt, partial, hist, esum, out);
  k_err  <<<GRID_SWZ, 256, 0, stream>>>(mf1, mf2, gt, partial, hist, esum);
  k_bins <<<NINST, 256, 0, stream>>>(hist, esum, partial, out);
}